// Round 1
// baseline (860.199 us; speedup 1.0000x reference)
//
#include <hip/hip_runtime.h>

// ---------------- constants ----------------
constexpr int kE   = 2048;   // entities
constexpr int kS   = 32;     // sequence length
constexpr int kD   = 256;    // ENT_DIM == REL_DIM == H
constexpr int kG4  = 1024;   // 4*H
constexpr int kK   = 512;    // concat K (x | h)
constexpr int kREL = 500;
constexpr int kN   = 1024;   // triples per polarity

typedef unsigned short u16;
typedef __attribute__((ext_vector_type(8))) _Float16 f16x8;
typedef __attribute__((ext_vector_type(4))) float    f32x4;

static __device__ __forceinline__ u16 f2h(float f) {
  _Float16 h = (_Float16)f;
  return __builtin_bit_cast(u16, h);
}

// ---------------- prep: weights -> fp16, concat [W_ih | W_hh] ----------------
__global__ void prep_weights(const float* __restrict__ Wih_f, const float* __restrict__ Whh_f,
                             const float* __restrict__ Wih_b, const float* __restrict__ Whh_b,
                             const float* __restrict__ Wlin_in,
                             u16* __restrict__ Wcat_f, u16* __restrict__ Wcat_b,
                             u16* __restrict__ Wlin) {
  int idx = blockIdx.x * 256 + threadIdx.x;
  if (idx < kG4 * kK) {
    int n = idx >> 9, k = idx & 511;
    float vf = (k < 256) ? Wih_f[n * 256 + k] : Whh_f[n * 256 + (k - 256)];
    float vb = (k < 256) ? Wih_b[n * 256 + k] : Whh_b[n * 256 + (k - 256)];
    Wcat_f[idx] = f2h(vf);
    Wcat_b[idx] = f2h(vb);
  }
  if (idx < 256 * kK) Wlin[idx] = f2h(Wlin_in[idx]);
}

// ---------------- gather x: x16[t][e][k] = fp16(ent_embed[neighbors[e][t]][k]) ----------------
__global__ void gather_x(const int* __restrict__ neighbors, const float* __restrict__ ent,
                         u16* __restrict__ x16) {
  const int tot = kS * kE * kD / 4;  // 4 elems per thread
  for (int i = blockIdx.x * blockDim.x + threadIdx.x; i < tot; i += gridDim.x * blockDim.x) {
    int k4 = i & 63;
    int row = i >> 6;               // t*kE + e
    int e = row & (kE - 1);
    int t = row >> 11;
    int nb = neighbors[e * kS + t];
    float4 v = *(const float4*)(ent + (size_t)nb * kD + k4 * 4);
    ushort4 o;
    o.x = f2h(v.x); o.y = f2h(v.y); o.z = f2h(v.z); o.w = f2h(v.w);
    *(ushort4*)(x16 + (size_t)row * kD + k4 * 4) = o;
  }
}

// ---------------- shared MFMA GEMM tile: 64 rows x 256 cols, K=512 ----------------
// A row-source: rows (e0+row), k<256 from Alo, k>=256 from Ahi (both row-stride 256, fp16)
// B: W[n][k] row-stride 512 fp16; GMAP maps tile col j -> n = (j>>6)*256 + u0 + (j&63)
template <bool GMAP>
static __device__ __forceinline__ void gemm_tile(
    const u16* __restrict__ Alo, const u16* __restrict__ Ahi,
    const u16* __restrict__ W, int e0, int u0,
    u16* As, u16* Bs, f32x4 (&acc)[4][4]) {
  const int tid = threadIdx.x;
  const int lane = tid & 63;
  const int w = tid >> 6;
#pragma unroll
  for (int m = 0; m < 4; m++)
#pragma unroll
    for (int n = 0; n < 4; n++) acc[m][n] = (f32x4){0.f, 0.f, 0.f, 0.f};

  for (int ch = 0; ch < 8; ++ch) {
    const int k0 = ch * 64;
    __syncthreads();
    const u16* Asrc = (k0 < 256) ? Alo : Ahi;
    const int kbase = (k0 < 256) ? k0 : (k0 - 256);
    // stage A: [64 rows][64 k] fp16, XOR-swizzled 16B units
#pragma unroll
    for (int i = 0; i < 2; i++) {
      int idx = tid + i * 256;
      int row = idx >> 3, c8 = idx & 7;
      uint4 v = *(const uint4*)(Asrc + (size_t)(e0 + row) * 256 + kbase + c8 * 8);
      *(uint4*)((char*)As + row * 128 + ((c8 * 16) ^ ((row & 7) << 4))) = v;
    }
    // stage B: [256 cols][64 k]
#pragma unroll
    for (int i = 0; i < 8; i++) {
      int idx = tid + i * 256;
      int j = idx >> 3, c8 = idx & 7;
      int n = GMAP ? ((j >> 6) * 256 + u0 + (j & 63)) : j;
      uint4 v = *(const uint4*)(W + (size_t)n * kK + k0 + c8 * 8);
      *(uint4*)((char*)Bs + j * 128 + ((c8 * 16) ^ ((j & 7) << 4))) = v;
    }
    __syncthreads();
#pragma unroll
    for (int ks = 0; ks < 2; ++ks) {
      const int kb = ks * 64 + (lane >> 4) * 16;  // byte offset of this lane's 8 fp16
      f16x8 a[4], b[4];
#pragma unroll
      for (int m = 0; m < 4; m++) {
        int row = m * 16 + (lane & 15);
        a[m] = *(const f16x8*)((const char*)As + row * 128 + (kb ^ ((row & 7) << 4)));
      }
#pragma unroll
      for (int n = 0; n < 4; n++) {
        int row = w * 64 + n * 16 + (lane & 15);
        b[n] = *(const f16x8*)((const char*)Bs + row * 128 + (kb ^ ((row & 7) << 4)));
      }
#pragma unroll
      for (int m = 0; m < 4; m++)
#pragma unroll
        for (int n = 0; n < 4; n++)
          acc[m][n] = __builtin_amdgcn_mfma_f32_16x16x32_f16(a[m], b[n], acc[m][n], 0, 0, 0);
    }
  }
}

// ---------------- one LSTM step, both directions (blockIdx.z) ----------------
__global__ __launch_bounds__(256) void lstm_step(
    const u16* __restrict__ x16, const u16* __restrict__ Wcat_f, const u16* __restrict__ Wcat_b,
    const float* __restrict__ b_f, const float* __restrict__ b_b,
    const u16* __restrict__ hprev, u16* __restrict__ hnext,
    float* __restrict__ cbuf, int t) {
  __shared__ __align__(16) char smem[65536];
  u16* As = (u16*)smem;                 // 8 KB
  u16* Bs = (u16*)(smem + 8192);        // 32 KB
  float* Gs = (float*)smem;             // 64 KB (aliases As/Bs after final barrier)

  const int tid = threadIdx.x, lane = tid & 63, w = tid >> 6;
  const int e0 = blockIdx.x * 64, u0 = blockIdx.y * 64, dir = blockIdx.z;

  const u16* Wd = dir ? Wcat_b : Wcat_f;
  const float* bd = dir ? b_b : b_f;
  const u16* xsrc = x16 + (size_t)(dir ? (kS - 1 - t) : t) * kE * kD;
  const u16* hp = hprev + (size_t)dir * kE * kD;
  u16* hn = hnext + (size_t)dir * kE * kD;
  float* cd = cbuf + (size_t)dir * kE * kD;

  f32x4 acc[4][4];
  gemm_tile<true>(xsrc, hp, Wd, e0, u0, As, Bs, acc);

  __syncthreads();
#pragma unroll
  for (int m = 0; m < 4; m++)
#pragma unroll
    for (int n = 0; n < 4; n++)
#pragma unroll
      for (int r = 0; r < 4; r++)
        Gs[(m * 16 + (lane >> 4) * 4 + r) * 256 + w * 64 + n * 16 + (lane & 15)] = acc[m][n][r];
  __syncthreads();

#pragma unroll
  for (int i = 0; i < 16; i++) {
    int cell = tid + i * 256;
    int er = cell >> 6, uu = cell & 63;
    float gi = Gs[er * 256 + uu]        + bd[u0 + uu];
    float gf = Gs[er * 256 + 64 + uu]   + bd[256 + u0 + uu];
    float gg = Gs[er * 256 + 128 + uu]  + bd[512 + u0 + uu];
    float go = Gs[er * 256 + 192 + uu]  + bd[768 + u0 + uu];
    size_t off = (size_t)(e0 + er) * kD + u0 + uu;
    float c_old = cd[off];
    float si = 1.f / (1.f + __expf(-gi));
    float sf = 1.f / (1.f + __expf(-gf));
    float so = 1.f / (1.f + __expf(-go));
    float cn = sf * c_old + si * tanhf(gg);
    cd[off] = cn;
    hn[off] = f2h(so * tanhf(cn));
  }
}

// ---------------- lin = [h_f | h_b] @ W_lin^T + b_lin ----------------
__global__ __launch_bounds__(256) void lin_kernel(
    const u16* __restrict__ hf, const u16* __restrict__ hb,
    const u16* __restrict__ Wl, const float* __restrict__ b_lin,
    float* __restrict__ lin) {
  __shared__ __align__(16) char smem[40960];
  u16* As = (u16*)smem;
  u16* Bs = (u16*)(smem + 8192);
  const int tid = threadIdx.x, lane = tid & 63, w = tid >> 6;
  const int e0 = blockIdx.x * 64;
  f32x4 acc[4][4];
  gemm_tile<false>(hf, hb, Wl, e0, 0, As, Bs, acc);
#pragma unroll
  for (int m = 0; m < 4; m++)
#pragma unroll
    for (int n = 0; n < 4; n++)
#pragma unroll
      for (int r = 0; r < 4; r++) {
        int e = e0 + m * 16 + (lane >> 4) * 4 + r;
        int col = w * 64 + n * 16 + (lane & 15);
        lin[(size_t)e * 256 + col] = acc[m][n][r] + b_lin[col];
      }
}

// ---------------- BatchNorm stats (training mode, biased var) + tanh ----------------
__global__ void bn_stats(const float* __restrict__ lin, float* __restrict__ part) {
  int b = blockIdx.x, c = threadIdx.x;  // grid 8
  float s = 0.f, s2 = 0.f;
  for (int e = b * 256; e < b * 256 + 256; ++e) {
    float x = lin[(size_t)e * 256 + c];
    s += x; s2 += x * x;
  }
  part[b * 256 + c] = s;
  part[2048 + b * 256 + c] = s2;
}

__global__ void bn_finalize(const float* __restrict__ part, float* __restrict__ mus) {
  int c = threadIdx.x;
  float s = 0.f, s2 = 0.f;
  for (int b = 0; b < 8; b++) { s += part[b * 256 + c]; s2 += part[2048 + b * 256 + c]; }
  float mu = s * (1.f / 2048.f);
  float var = s2 * (1.f / 2048.f) - mu * mu;
  mus[c] = mu;
  mus[256 + c] = rsqrtf(var + 1e-5f);
}

__global__ void bn_tanh(const float* __restrict__ lin, const float* __restrict__ mus,
                        const float* __restrict__ gamma, const float* __restrict__ beta,
                        float* __restrict__ ctx) {
  int idx = blockIdx.x * 256 + threadIdx.x;  // grid 2048
  int c = idx & 255;
  float x = lin[idx];
  ctx[idx] = tanhf(gamma[c] * (x - mus[c]) * mus[256 + c] + beta[c]);
}

// ---------------- scores: one block per triple ----------------
__global__ __launch_bounds__(256) void score_kernel(
    const float* __restrict__ ctx, const float* __restrict__ trans,
    const float* __restrict__ rel_embed,
    const int* __restrict__ ph, const int* __restrict__ pt, const int* __restrict__ pr,
    const int* __restrict__ nh, const int* __restrict__ nt, const int* __restrict__ nr,
    float* __restrict__ scores) {
  int n = blockIdx.x;
  bool pos = n < kN;
  int m = n & (kN - 1);
  int hi = pos ? ph[m] : nh[m];
  int ti = pos ? pt[m] : nt[m];
  int ri = pos ? pr[m] : nr[m];
  __shared__ float ch[256], ct[256];
  __shared__ float wsum[4];
  int tid = threadIdx.x;
  ch[tid] = ctx[(size_t)hi * 256 + tid];
  ct[tid] = ctx[(size_t)ti * 256 + tid];
  __syncthreads();
  const float4* Wh = (const float4*)(trans + (size_t)ri * 65536 + (size_t)tid * 256);
  const float4* Wt = (const float4*)(trans + ((size_t)ri + kREL) * 65536 + (size_t)tid * 256);
  const float4* c4h = (const float4*)ch;
  const float4* c4t = (const float4*)ct;
  float acc = rel_embed[ri * 256 + tid];
#pragma unroll 4
  for (int q = 0; q < 64; q++) {
    float4 w1 = Wh[q], x1 = c4h[q];
    float4 w2 = Wt[q], x2 = c4t[q];
    acc += w1.x * x1.x + w1.y * x1.y + w1.z * x1.z + w1.w * x1.w;
    acc -= w2.x * x2.x + w2.y * x2.y + w2.z * x2.z + w2.w * x2.w;
  }
  float sq = acc * acc;
  for (int off = 32; off; off >>= 1) sq += __shfl_down(sq, off);
  if ((tid & 63) == 0) wsum[tid >> 6] = sq;
  __syncthreads();
  if (tid == 0) scores[n] = sqrtf(wsum[0] + wsum[1] + wsum[2] + wsum[3]);
}

__global__ void final_reduce(const float* __restrict__ scores, float* __restrict__ out) {
  int tid = threadIdx.x;
  float a = 0.f;
  for (int i = tid; i < 2 * kN; i += 256) {
    float s = scores[i];
    a += (i < kN) ? s : fmaxf(0.f, 1.f - s);
  }
  for (int off = 32; off; off >>= 1) a += __shfl_down(a, off);
  __shared__ float w4[4];
  if ((tid & 63) == 0) w4[tid >> 6] = a;
  __syncthreads();
  if (tid == 0) out[0] = w4[0] + w4[1] + w4[2] + w4[3];
}

// ---------------- host ----------------
extern "C" void kernel_launch(void* const* d_in, const int* in_sizes, int n_in,
                              void* d_out, int out_size, void* d_ws, size_t ws_size,
                              hipStream_t stream) {
  const int*   neighbors = (const int*)d_in[0];
  const int*   pos_h = (const int*)d_in[1];
  const int*   pos_t = (const int*)d_in[2];
  const int*   pos_r = (const int*)d_in[3];
  const int*   neg_h = (const int*)d_in[4];
  const int*   neg_t = (const int*)d_in[5];
  const int*   neg_r = (const int*)d_in[6];
  const float* ent_embed = (const float*)d_in[7];
  const float* rel_embed = (const float*)d_in[8];
  const float* trans = (const float*)d_in[9];
  const float* W_ih_f = (const float*)d_in[10];
  const float* W_hh_f = (const float*)d_in[11];
  const float* W_ih_b = (const float*)d_in[12];
  const float* W_hh_b = (const float*)d_in[13];
  const float* b_f = (const float*)d_in[14];
  const float* b_b = (const float*)d_in[15];
  const float* W_lin = (const float*)d_in[16];
  const float* b_lin = (const float*)d_in[17];
  const float* gamma = (const float*)d_in[18];
  const float* beta = (const float*)d_in[19];

  char* ws = (char*)d_ws;
  size_t off = 0;
  auto alloc = [&](size_t bytes) {
    void* p = ws + off;
    off = (off + bytes + 255) & ~(size_t)255;
    return p;
  };
  u16* Wcat_f = (u16*)alloc((size_t)kG4 * kK * 2);
  u16* Wcat_b = (u16*)alloc((size_t)kG4 * kK * 2);
  u16* Wlin   = (u16*)alloc((size_t)256 * kK * 2);
  u16* x16    = (u16*)alloc((size_t)kS * kE * kD * 2);
  u16* hbuf0  = (u16*)alloc((size_t)2 * kE * kD * 2);  // [dir][E][H]
  u16* hbuf1  = (u16*)alloc((size_t)2 * kE * kD * 2);
  float* cbuf = (float*)alloc((size_t)2 * kE * kD * 4);
  float* lin  = (float*)alloc((size_t)kE * 256 * 4);
  float* part = (float*)alloc((size_t)2 * 8 * 256 * 4);
  float* mus  = (float*)alloc((size_t)2 * 256 * 4);
  float* ctx  = (float*)alloc((size_t)kE * 256 * 4);
  float* scores = (float*)alloc((size_t)2 * kN * 4);
  (void)ws_size; (void)in_sizes; (void)n_in; (void)out_size;

  hipMemsetAsync(hbuf0, 0, (size_t)2 * kE * kD * 2, stream);
  hipMemsetAsync(cbuf, 0, (size_t)2 * kE * kD * 4, stream);

  prep_weights<<<2048, 256, 0, stream>>>(W_ih_f, W_hh_f, W_ih_b, W_hh_b, W_lin,
                                         Wcat_f, Wcat_b, Wlin);
  gather_x<<<4096, 256, 0, stream>>>(neighbors, ent_embed, x16);

  for (int t = 0; t < kS; ++t) {
    const u16* hp = (t & 1) ? hbuf1 : hbuf0;
    u16* hn = (t & 1) ? hbuf0 : hbuf1;
    lstm_step<<<dim3(32, 4, 2), 256, 0, stream>>>(x16, Wcat_f, Wcat_b, b_f, b_b, hp, hn, cbuf, t);
  }
  // after t=31 (odd), final h is in hbuf0
  lin_kernel<<<dim3(32, 1), 256, 0, stream>>>(hbuf0, hbuf0 + (size_t)kE * kD, Wlin, b_lin, lin);
  bn_stats<<<8, 256, 0, stream>>>(lin, part);
  bn_finalize<<<1, 256, 0, stream>>>(part, mus);
  bn_tanh<<<2048, 256, 0, stream>>>(lin, mus, gamma, beta, ctx);
  score_kernel<<<2 * kN, 256, 0, stream>>>(ctx, trans, rel_embed,
                                           pos_h, pos_t, pos_r, neg_h, neg_t, neg_r, scores);
  final_reduce<<<1, 256, 0, stream>>>(scores, (float*)d_out);
}

// Round 3
// 858.125 us; speedup vs baseline: 1.0024x; 1.0024x over previous
//
#include <hip/hip_runtime.h>

// ---------------- constants ----------------
constexpr int kE   = 2048;   // entities
constexpr int kS   = 32;     // sequence length
constexpr int kD   = 256;    // ENT_DIM == REL_DIM == H
constexpr int kG4  = 1024;   // 4*H
constexpr int kK   = 512;    // concat K (x | h)
constexpr int kREL = 500;
constexpr int kN   = 1024;   // triples per polarity

typedef unsigned short u16;
typedef __attribute__((ext_vector_type(8))) _Float16 f16x8;
typedef __attribute__((ext_vector_type(4))) float    f32x4;

static __device__ __forceinline__ u16 f2h(float f) {
  _Float16 h = (_Float16)f;
  return __builtin_bit_cast(u16, h);
}
static __device__ __forceinline__ float sigf(float x) { return 1.f / (1.f + __expf(-x)); }
static __device__ __forceinline__ float tanhfast(float x) {
  float e = __expf(2.f * x);
  return 1.f - 2.f / (e + 1.f);
}

// ---------------- prep: weights -> fp16; LSTM weights gate-interleave-reordered ----------------
// Wr[dir][row'][k]: row' = (u>>4)*64 + g*16 + (u&15)  (u = unit 0..255, g = gate i,f,g,o)
__global__ void prep_weights(const float* __restrict__ Wih_f, const float* __restrict__ Whh_f,
                             const float* __restrict__ Wih_b, const float* __restrict__ Whh_b,
                             const float* __restrict__ Wlin_in,
                             u16* __restrict__ Wr, u16* __restrict__ Wlin) {
  int idx = blockIdx.x * 256 + threadIdx.x;
  if (idx < kG4 * kK) {
    int rp = idx >> 9, k = idx & 511;
    int g = (rp >> 4) & 3;
    int u = (rp >> 6) * 16 + (rp & 15);
    int row = g * 256 + u;
    float vf, vb;
    if (k < 256) { vf = Wih_f[row * 256 + k];        vb = Wih_b[row * 256 + k]; }
    else         { vf = Whh_f[row * 256 + k - 256];  vb = Whh_b[row * 256 + k - 256]; }
    Wr[idx] = f2h(vf);
    Wr[kG4 * kK + idx] = f2h(vb);
  }
  if (idx < 256 * kK) Wlin[idx] = f2h(Wlin_in[idx]);
}

// ---------------- gather x: x16[t][e][k] = fp16(ent_embed[neighbors[e][t]][k]) ----------------
__global__ void gather_x(const int* __restrict__ neighbors, const float* __restrict__ ent,
                         u16* __restrict__ x16) {
  const int tot = kS * kE * kD / 4;
  for (int i = blockIdx.x * blockDim.x + threadIdx.x; i < tot; i += gridDim.x * blockDim.x) {
    int k4 = i & 63;
    int row = i >> 6;               // t*kE + e
    int e = row & (kE - 1);
    int t = row >> 11;
    int nb = neighbors[e * kS + t];
    float4 v = *(const float4*)(ent + (size_t)nb * kD + k4 * 4);
    ushort4 o;
    o.x = f2h(v.x); o.y = f2h(v.y); o.z = f2h(v.z); o.w = f2h(v.w);
    *(ushort4*)(x16 + (size_t)row * kD + k4 * 4) = o;
  }
}

// ---------------- one LSTM step, gates combined in-register (no LDS, no barriers) ----------------
// grid 256 blocks x 256 thr. Block = (dir, ut, et); wave tile 64 rows x 64 cols'.
__global__ __launch_bounds__(256) void lstm_step_reg(
    const u16* __restrict__ x16, const u16* __restrict__ Wr,
    const float* __restrict__ b_f, const float* __restrict__ b_b,
    const u16* __restrict__ hprev, u16* __restrict__ hnext,
    float* __restrict__ cbuf, int t) {
  const int tid = threadIdx.x, lane = tid & 63, w = tid >> 6;
  const int bid = blockIdx.x;
  const int dir = bid >> 7;
  const int ut  = (bid >> 4) & 7;
  const int et  = bid & 15;
  const int wr = w >> 1, wc = w & 1;
  const int e0 = et * 128 + wr * 64;
  const int c0 = ut * 128 + wc * 64;             // col' base (16 units x 4 gates)
  const int unit = (c0 >> 6) * 16 + (lane & 15); // global unit for this lane

  const float* bd = dir ? b_b : b_f;
  const u16* Wd  = Wr + (size_t)dir * kG4 * kK;
  const u16* xs  = x16 + (size_t)(dir ? (kS - 1 - t) : t) * kE * kD;
  const u16* hpd = hprev + (size_t)dir * kE * kD;
  u16* hnd = hnext + (size_t)dir * kE * kD;
  float* cd = cbuf + (size_t)dir * kE * kD;

  const int klane = (lane >> 4) * 8;

  f32x4 acc[4][4];
#pragma unroll
  for (int m = 0; m < 4; m++)
#pragma unroll
    for (int n = 0; n < 4; n++) acc[m][n] = (f32x4){0.f, 0.f, 0.f, 0.f};

#pragma unroll
  for (int ks = 0; ks < 16; ks++) {
    const u16* asrc = (ks < 8) ? xs : hpd;
    const int ka = (ks & 7) * 32 + klane;
    f16x8 a[4], b[4];
#pragma unroll
    for (int m = 0; m < 4; m++) {
      int row = e0 + m * 16 + (lane & 15);
      a[m] = *(const f16x8*)(asrc + (size_t)row * kD + ka);
    }
#pragma unroll
    for (int n = 0; n < 4; n++) {
      int rowp = c0 + n * 16 + (lane & 15);
      b[n] = *(const f16x8*)(Wd + (size_t)rowp * kK + ks * 32 + klane);
    }
#pragma unroll
    for (int m = 0; m < 4; m++)
#pragma unroll
      for (int n = 0; n < 4; n++)
        acc[m][n] = __builtin_amdgcn_mfma_f32_16x16x32_f16(a[m], b[n], acc[m][n], 0, 0, 0);
  }

  const float bi = bd[unit], bf_ = bd[256 + unit], bg = bd[512 + unit], bo = bd[768 + unit];
#pragma unroll
  for (int m = 0; m < 4; m++)
#pragma unroll
    for (int r = 0; r < 4; r++) {
      int row = e0 + m * 16 + (lane >> 4) * 4 + r;
      size_t off = (size_t)row * kD + unit;
      float gi = acc[m][0][r] + bi;
      float gf = acc[m][1][r] + bf_;
      float gg = acc[m][2][r] + bg;
      float go = acc[m][3][r] + bo;
      float c_old = cd[off];
      float cn = sigf(gf) * c_old + sigf(gi) * tanhfast(gg);
      cd[off] = cn;
      hnd[off] = f2h(sigf(go) * tanhfast(cn));
    }
}

// ---------------- shared MFMA GEMM tile (used by lin): 64 rows x 256 cols, K=512 ----------------
template <bool GMAP>
static __device__ __forceinline__ void gemm_tile(
    const u16* __restrict__ Alo, const u16* __restrict__ Ahi,
    const u16* __restrict__ W, int e0, int u0,
    u16* As, u16* Bs, f32x4 (&acc)[4][4]) {
  const int tid = threadIdx.x;
  const int lane = tid & 63;
  const int w = tid >> 6;
#pragma unroll
  for (int m = 0; m < 4; m++)
#pragma unroll
    for (int n = 0; n < 4; n++) acc[m][n] = (f32x4){0.f, 0.f, 0.f, 0.f};

  for (int ch = 0; ch < 8; ++ch) {
    const int k0 = ch * 64;
    __syncthreads();
    const u16* Asrc = (k0 < 256) ? Alo : Ahi;
    const int kbase = (k0 < 256) ? k0 : (k0 - 256);
#pragma unroll
    for (int i = 0; i < 2; i++) {
      int idx = tid + i * 256;
      int row = idx >> 3, c8 = idx & 7;
      uint4 v = *(const uint4*)(Asrc + (size_t)(e0 + row) * 256 + kbase + c8 * 8);
      *(uint4*)((char*)As + row * 128 + ((c8 * 16) ^ ((row & 7) << 4))) = v;
    }
#pragma unroll
    for (int i = 0; i < 8; i++) {
      int idx = tid + i * 256;
      int j = idx >> 3, c8 = idx & 7;
      int n = GMAP ? ((j >> 6) * 256 + u0 + (j & 63)) : j;
      uint4 v = *(const uint4*)(W + (size_t)n * kK + k0 + c8 * 8);
      *(uint4*)((char*)Bs + j * 128 + ((c8 * 16) ^ ((j & 7) << 4))) = v;
    }
    __syncthreads();
#pragma unroll
    for (int ks = 0; ks < 2; ++ks) {
      const int kb = ks * 64 + (lane >> 4) * 16;
      f16x8 a[4], b[4];
#pragma unroll
      for (int m = 0; m < 4; m++) {
        int row = m * 16 + (lane & 15);
        a[m] = *(const f16x8*)((const char*)As + row * 128 + (kb ^ ((row & 7) << 4)));
      }
#pragma unroll
      for (int n = 0; n < 4; n++) {
        int row = w * 64 + n * 16 + (lane & 15);
        b[n] = *(const f16x8*)((const char*)Bs + row * 128 + (kb ^ ((row & 7) << 4)));
      }
#pragma unroll
      for (int m = 0; m < 4; m++)
#pragma unroll
        for (int n = 0; n < 4; n++)
          acc[m][n] = __builtin_amdgcn_mfma_f32_16x16x32_f16(a[m], b[n], acc[m][n], 0, 0, 0);
    }
  }
}

// ---------------- lin = [h_f | h_b] @ W_lin^T + b_lin ----------------
__global__ __launch_bounds__(256) void lin_kernel(
    const u16* __restrict__ hf, const u16* __restrict__ hb,
    const u16* __restrict__ Wl, const float* __restrict__ b_lin,
    float* __restrict__ lin) {
  __shared__ __align__(16) char smem[40960];
  u16* As = (u16*)smem;
  u16* Bs = (u16*)(smem + 8192);
  const int tid = threadIdx.x, lane = tid & 63, w = tid >> 6;
  const int e0 = blockIdx.x * 64;
  f32x4 acc[4][4];
  gemm_tile<false>(hf, hb, Wl, e0, 0, As, Bs, acc);
#pragma unroll
  for (int m = 0; m < 4; m++)
#pragma unroll
    for (int n = 0; n < 4; n++)
#pragma unroll
      for (int r = 0; r < 4; r++) {
        int e = e0 + m * 16 + (lane >> 4) * 4 + r;
        int col = w * 64 + n * 16 + (lane & 15);
        lin[(size_t)e * 256 + col] = acc[m][n][r] + b_lin[col];
      }
}

// ---------------- BatchNorm stats (training mode, biased var) + tanh ----------------
__global__ void bn_stats(const float* __restrict__ lin, float* __restrict__ part) {
  int b = blockIdx.x, c = threadIdx.x;
  float s = 0.f, s2 = 0.f;
  for (int e = b * 256; e < b * 256 + 256; ++e) {
    float x = lin[(size_t)e * 256 + c];
    s += x; s2 += x * x;
  }
  part[b * 256 + c] = s;
  part[2048 + b * 256 + c] = s2;
}

__global__ void bn_finalize(const float* __restrict__ part, float* __restrict__ mus) {
  int c = threadIdx.x;
  float s = 0.f, s2 = 0.f;
  for (int b = 0; b < 8; b++) { s += part[b * 256 + c]; s2 += part[2048 + b * 256 + c]; }
  float mu = s * (1.f / 2048.f);
  float var = s2 * (1.f / 2048.f) - mu * mu;
  mus[c] = mu;
  mus[256 + c] = rsqrtf(var + 1e-5f);
}

__global__ void bn_tanh(const float* __restrict__ lin, const float* __restrict__ mus,
                        const float* __restrict__ gamma, const float* __restrict__ beta,
                        float* __restrict__ ctx) {
  int idx = blockIdx.x * 256 + threadIdx.x;
  int c = idx & 255;
  float x = lin[idx];
  ctx[idx] = tanhf(gamma[c] * (x - mus[c]) * mus[256 + c] + beta[c]);
}

// ---------------- relation grouping ----------------
__global__ void count_rel(const int* __restrict__ pr, const int* __restrict__ nr,
                          int* __restrict__ counts) {
  int i = blockIdx.x * 256 + threadIdx.x;
  if (i < kN) atomicAdd(&counts[pr[i]], 1);
  else if (i < 2 * kN) atomicAdd(&counts[nr[i - kN]], 1);
}

__global__ void scan_rel(const int* __restrict__ counts, int* __restrict__ offs) {
  __shared__ int s[512];
  int tid = threadIdx.x;
  s[tid] = (tid < kREL) ? counts[tid] : 0;
  __syncthreads();
  for (int d = 1; d < 512; d <<= 1) {
    int v = (tid >= d) ? s[tid - d] : 0;
    __syncthreads();
    s[tid] += v;
    __syncthreads();
  }
  if (tid == 0) offs[0] = 0;
  if (tid <= kREL) offs[tid + 1] = s[tid];
}

__global__ void scatter_rel(const int* __restrict__ pr, const int* __restrict__ nr,
                            const int* __restrict__ offs, int* __restrict__ cursor,
                            int* __restrict__ list) {
  int i = blockIdx.x * 256 + threadIdx.x;
  if (i >= 2 * kN) return;
  int r = (i < kN) ? pr[i] : nr[i - kN];
  int p = atomicAdd(&cursor[r], 1);
  list[offs[r] + p] = i;
}

// ---------------- scores: one block per RELATION (W read once per relation) ----------------
__global__ __launch_bounds__(256) void score_grouped(
    const float* __restrict__ ctx, const float* __restrict__ trans,
    const float* __restrict__ rel_embed,
    const int* __restrict__ ph, const int* __restrict__ pt,
    const int* __restrict__ nh, const int* __restrict__ nt,
    const int* __restrict__ offs, const int* __restrict__ list,
    float* __restrict__ scores) {
  int r = blockIdx.x;
  int start = offs[r], end = offs[r + 1];
  if (start >= end) return;
  int tid = threadIdx.x;
  __shared__ float cs[8][2][256];
  __shared__ float red[8][4];
  float relv = rel_embed[r * 256 + tid];
  const float4* Whp = (const float4*)(trans + (size_t)r * 65536 + (size_t)tid * 256);
  const float4* Wtp = (const float4*)(trans + ((size_t)r + kREL) * 65536 + (size_t)tid * 256);

  for (int chunk = start; chunk < end; chunk += 8) {
    int G = min(8, end - chunk);
    for (int j = 0; j < G; j++) {
      int i = list[chunk + j];
      int hh = (i < kN) ? ph[i] : nh[i - kN];
      int tt = (i < kN) ? pt[i] : nt[i - kN];
      cs[j][0][tid] = ctx[(size_t)hh * 256 + tid];
      cs[j][1][tid] = ctx[(size_t)tt * 256 + tid];
    }
    __syncthreads();
    float acc[8];
#pragma unroll
    for (int j = 0; j < 8; j++) acc[j] = relv;
#pragma unroll 2
    for (int q = 0; q < 64; q++) {
      float4 w1 = Whp[q];
      float4 w2 = Wtp[q];
#pragma unroll
      for (int j = 0; j < 8; j++) {
        float4 xh = *(const float4*)&cs[j][0][q * 4];
        float4 xt = *(const float4*)&cs[j][1][q * 4];
        acc[j] += w1.x * xh.x + w1.y * xh.y + w1.z * xh.z + w1.w * xh.w
                - (w2.x * xt.x + w2.y * xt.y + w2.z * xt.z + w2.w * xt.w);
      }
    }
    for (int j = 0; j < G; j++) {
      float sq = acc[j] * acc[j];
      for (int o = 32; o; o >>= 1) sq += __shfl_down(sq, o);
      if ((tid & 63) == 0) red[j][tid >> 6] = sq;
    }
    __syncthreads();
    if (tid < G) {
      float s = red[tid][0] + red[tid][1] + red[tid][2] + red[tid][3];
      scores[list[chunk + tid]] = sqrtf(s);
    }
    __syncthreads();
  }
}

__global__ void final_reduce(const float* __restrict__ scores, float* __restrict__ out) {
  int tid = threadIdx.x;
  float a = 0.f;
  for (int i = tid; i < 2 * kN; i += 256) {
    float s = scores[i];
    a += (i < kN) ? s : fmaxf(0.f, 1.f - s);
  }
  for (int off = 32; off; off >>= 1) a += __shfl_down(a, off);
  __shared__ float w4[4];
  if ((tid & 63) == 0) w4[tid >> 6] = a;
  __syncthreads();
  if (tid == 0) out[0] = w4[0] + w4[1] + w4[2] + w4[3];
}

// ---------------- host ----------------
extern "C" void kernel_launch(void* const* d_in, const int* in_sizes, int n_in,
                              void* d_out, int out_size, void* d_ws, size_t ws_size,
                              hipStream_t stream) {
  const int*   neighbors = (const int*)d_in[0];
  const int*   pos_h = (const int*)d_in[1];
  const int*   pos_t = (const int*)d_in[2];
  const int*   pos_r = (const int*)d_in[3];
  const int*   neg_h = (const int*)d_in[4];
  const int*   neg_t = (const int*)d_in[5];
  const int*   neg_r = (const int*)d_in[6];
  const float* ent_embed = (const float*)d_in[7];
  const float* rel_embed = (const float*)d_in[8];
  const float* trans = (const float*)d_in[9];
  const float* W_ih_f = (const float*)d_in[10];
  const float* W_hh_f = (const float*)d_in[11];
  const float* W_ih_b = (const float*)d_in[12];
  const float* W_hh_b = (const float*)d_in[13];
  const float* b_f = (const float*)d_in[14];
  const float* b_b = (const float*)d_in[15];
  const float* W_lin = (const float*)d_in[16];
  const float* b_lin = (const float*)d_in[17];
  const float* gamma = (const float*)d_in[18];
  const float* beta = (const float*)d_in[19];

  char* ws = (char*)d_ws;
  size_t off = 0;
  auto alloc = [&](size_t bytes) {
    void* p = ws + off;
    off = (off + bytes + 255) & ~(size_t)255;
    return p;
  };
  u16* Wr     = (u16*)alloc((size_t)2 * kG4 * kK * 2);
  u16* Wlin   = (u16*)alloc((size_t)256 * kK * 2);
  u16* x16    = (u16*)alloc((size_t)kS * kE * kD * 2);
  u16* h0     = (u16*)alloc((size_t)2 * kE * kD * 2);
  u16* h1     = (u16*)alloc((size_t)2 * kE * kD * 2);
  float* cbuf = (float*)alloc((size_t)2 * kE * kD * 4);
  float* lin  = (float*)alloc((size_t)kE * 256 * 4);
  float* part = (float*)alloc((size_t)2 * 8 * 256 * 4);
  float* mus  = (float*)alloc((size_t)2 * 256 * 4);
  float* ctx  = (float*)alloc((size_t)kE * 256 * 4);
  float* scores = (float*)alloc((size_t)2 * kN * 4);
  int* zz     = (int*)alloc((size_t)1024 * 4);  // counts | cursor
  int* counts = zz;
  int* cursor = zz + 512;
  int* offsb  = (int*)alloc((size_t)520 * 4);
  int* list   = (int*)alloc((size_t)2 * kN * 4);
  (void)ws_size; (void)in_sizes; (void)n_in; (void)out_size;

  hipMemsetAsync(h0, 0, (size_t)2 * kE * kD * 2, stream);
  hipMemsetAsync(cbuf, 0, (size_t)2 * kE * kD * 4, stream);
  hipMemsetAsync(zz, 0, (size_t)1024 * 4, stream);

  prep_weights<<<2048, 256, 0, stream>>>(W_ih_f, W_hh_f, W_ih_b, W_hh_b, W_lin, Wr, Wlin);
  gather_x<<<4096, 256, 0, stream>>>(neighbors, ent_embed, x16);
  count_rel<<<8, 256, 0, stream>>>(pos_r, neg_r, counts);
  scan_rel<<<1, 512, 0, stream>>>(counts, offsb);
  scatter_rel<<<8, 256, 0, stream>>>(pos_r, neg_r, offsb, cursor, list);

  for (int t = 0; t < kS; ++t) {
    const u16* hp = (t & 1) ? h1 : h0;
    u16* hn = (t & 1) ? h0 : h1;
    lstm_step_reg<<<256, 256, 0, stream>>>(x16, Wr, b_f, b_b, hp, hn, cbuf, t);
  }

  // after t=31 (odd), final h (both dirs) is in h0
  lin_kernel<<<dim3(32, 1), 256, 0, stream>>>(h0, h0 + (size_t)kE * kD, Wlin, b_lin, lin);
  bn_stats<<<8, 256, 0, stream>>>(lin, part);
  bn_finalize<<<1, 256, 0, stream>>>(part, mus);
  bn_tanh<<<2048, 256, 0, stream>>>(lin, mus, gamma, beta, ctx);
  score_grouped<<<kREL, 256, 0, stream>>>(ctx, trans, rel_embed,
                                          pos_h, pos_t, neg_h, neg_t, offsb, list, scores);
  final_reduce<<<1, 256, 0, stream>>>(scores, (float*)d_out);
}